// Round 1
// baseline (30237.607 us; speedup 1.0000x reference)
//
#include <hip/hip_runtime.h>
#include <cstdint>
#include <cstddef>

// ---------------------------------------------------------------------------
// GConvGRU (ChebConv K=3, 2 layers) + readout, for MI355X.
// Strategy: build CSR (by destination) once per call, pull-based SpMM with
// batch folded into feature dim, fused gate kernels, streaming over timesteps.
// ---------------------------------------------------------------------------

__device__ __forceinline__ float sigmoidf_(float x){ return 1.f/(1.f+__expf(-x)); }

// ---------------- preprocessing ----------------

// If edge_index is int64, every odd dword (high word) of the buffer is 0
// (all indices < 50000). If int32, odd dwords are real indices (~0 prob all 0).
__global__ void detect_kernel(const unsigned* __restrict__ buf, int ndw, int* flag){
  int i = blockIdx.x*blockDim.x + threadIdx.x;
  int j = 2*i + 1;
  if (j < ndw && buf[j] != 0u) atomicOr(flag, 1);   // flag=1 -> int32
}

__global__ void convert_kernel(const void* __restrict__ eidx, const float* __restrict__ w,
                               int E, const int* __restrict__ flag,
                               int* __restrict__ row32, int* __restrict__ col32,
                               float* __restrict__ deg, int* __restrict__ cnt){
  int e = blockIdx.x*blockDim.x + threadIdx.x;
  if (e >= E) return;
  int r, c;
  if (*flag){ const int* p = (const int*)eidx; r = p[e]; c = p[E+e]; }
  else { const long long* p = (const long long*)eidx; r = (int)p[e]; c = (int)p[(size_t)E+e]; }
  row32[e] = r; col32[e] = c;
  atomicAdd(deg + r, w[e]);
  atomicAdd(cnt + c, 1);
}

__global__ void node_prep_kernel(const float* __restrict__ deg, float* __restrict__ dinv,
                                 float* __restrict__ dg, int N){
  int n = blockIdx.x*blockDim.x + threadIdx.x;
  if (n >= N) return;
  float d = deg[n];
  if (d > 0.f){ dinv[n] = rsqrtf(d); dg[n] = 0.f; }
  else        { dinv[n] = 0.f;       dg[n] = -1.f; }
}

// Exclusive scan of cnt[N] -> ptr[N+1], single block of 1024 threads.
__global__ void scan_kernel(const int* __restrict__ cnt, int* __restrict__ ptrout, int N){
  __shared__ int s[1024];
  int t = threadIdx.x;
  int chunk = (N + 1023) / 1024;
  int a0 = t*chunk, a1 = min(N, a0 + chunk);
  int sum = 0;
  for (int i = a0; i < a1; ++i) sum += cnt[i];
  s[t] = sum; __syncthreads();
  for (int off = 1; off < 1024; off <<= 1){
    int v = (t >= off) ? s[t-off] : 0;
    __syncthreads();
    s[t] += v;
    __syncthreads();
  }
  int run = (t == 0) ? 0 : s[t-1];
  for (int i = a0; i < a1; ++i){ ptrout[i] = run; run += cnt[i]; }
  if (t == 1023) ptrout[N] = s[1023];
}

__global__ void fill_kernel(const int* __restrict__ row32, const int* __restrict__ col32,
                            const float* __restrict__ w, const float* __restrict__ dinv,
                            const int* __restrict__ ptrv, int* __restrict__ cnt2,
                            int* __restrict__ srcs, float* __restrict__ vals, int E){
  int e = blockIdx.x*blockDim.x + threadIdx.x;
  if (e >= E) return;
  int r = row32[e], c = col32[e];
  int p = ptrv[c] + atomicAdd(cnt2 + c, 1);
  srcs[p] = r;
  vals[p] = -w[e] * dinv[r] * dinv[c];
}

// ---------------- SpMM: y = alpha*(A x + diag*x) + beta*z ----------------
// Pull-based CSR. FW = features per node handled by FW consecutive threads.
template<int FW>
__global__ __launch_bounds__(128) void spmm_kernel(
    const int* __restrict__ ptrv, const int* __restrict__ srcs, const float* __restrict__ vals,
    const float* __restrict__ dg, const float* __restrict__ x, const float* __restrict__ z,
    float* __restrict__ y, int N, int ld, float alpha, float beta){
  constexpr int NPB = 128 / FW;
  int t = threadIdx.x;
  int node = blockIdx.x*NPB + t/FW;
  if (node >= N) return;
  int f = t % FW;
  int e0 = ptrv[node], e1 = ptrv[node+1];
  float acc = 0.f;
  for (int e = e0; e < e1; ++e){
    int s = srcs[e];
    float v = vals[e];
    acc = fmaf(v, x[(size_t)s*ld + f], acc);
  }
  size_t ii = (size_t)node*ld + f;
  float r = alpha*(acc + dg[node]*x[ii]);
  if (z) r = fmaf(beta, z[ii], r);
  y[ii] = r;
}

// ---------------- transpose layer-0 input: [B,T,N,8] -> [N, B*8] for step t ----
__global__ void transpose_x_kernel(const float* __restrict__ in, float* __restrict__ out,
                                   int N, int t){
  int idx = blockIdx.x*blockDim.x + threadIdx.x;   // over N*32
  if (idx >= N*32) return;
  int n = idx >> 5; int r = idx & 31; int b = r >> 3; int i = r & 7;
  out[idx] = in[(((size_t)b*12 + t)*N + n)*8 + i];
}

// ---------------- gate A: Z, R, HR, gx2 ----------------
// One node per block; 128 threads = (b = t/32, h = t%32).
template<int FIN>
__global__ __launch_bounds__(128) void gateA_kernel(
    const float* __restrict__ xT0, const float* __restrict__ xT1, const float* __restrict__ xT2,
    int xld,
    const float* __restrict__ H, const float* __restrict__ th1, const float* __restrict__ th2,
    const float* __restrict__ Wx, const float* __restrict__ bx,
    const float* __restrict__ Whz, const float* __restrict__ Whr,
    const float* __restrict__ bhz, const float* __restrict__ bhr,
    float* __restrict__ Zb, float* __restrict__ gx2b, float* __restrict__ HRb, int N){
  int n = blockIdx.x;
  int t = threadIdx.x; int b = t >> 5; int h = t & 31;
  __shared__ float sx[3][4*FIN];
  __shared__ float sh[3][128];
  for (int i = t; i < 4*FIN; i += 128){
    sx[0][i] = xT0[(size_t)n*xld + i];
    sx[1][i] = xT1[(size_t)n*xld + i];
    sx[2][i] = xT2[(size_t)n*xld + i];
  }
  sh[0][t] = H  [(size_t)n*128 + t];
  sh[1][t] = th1[(size_t)n*128 + t];
  sh[2][t] = th2[(size_t)n*128 + t];
  __syncthreads();
  float g0 = bx[h], g1 = bx[32+h], g2 = bx[64+h];
  #pragma unroll
  for (int k = 0; k < 3; ++k){
    #pragma unroll
    for (int i = 0; i < FIN; ++i){
      float xv = sx[k][b*FIN + i];
      g0 = fmaf(xv, Wx[((0*3 + k)*FIN + i)*32 + h], g0);
      g1 = fmaf(xv, Wx[((1*3 + k)*FIN + i)*32 + h], g1);
      g2 = fmaf(xv, Wx[((2*3 + k)*FIN + i)*32 + h], g2);
    }
  }
  float gz = bhz[h], gr = bhr[h];
  #pragma unroll
  for (int k = 0; k < 3; ++k){
    #pragma unroll
    for (int o = 0; o < 32; ++o){
      float hv = sh[k][b*32 + o];
      gz = fmaf(hv, Whz[(k*32 + o)*32 + h], gz);
      gr = fmaf(hv, Whr[(k*32 + o)*32 + h], gr);
    }
  }
  float Z = sigmoidf_(g0 + gz);
  float R = sigmoidf_(g1 + gr);
  size_t idx = (size_t)n*128 + t;
  Zb[idx]   = Z;
  gx2b[idx] = g2;
  HRb[idx]  = sh[0][t] * R;
}

// ---------------- gate B: H = Z*H + (1-Z)*tanh(gx2 + THR.Wh2) ----------------
__global__ __launch_bounds__(128) void gateB_kernel(
    const float* __restrict__ thr0, const float* __restrict__ thr1, const float* __restrict__ thr2,
    const float* __restrict__ Whh, const float* __restrict__ bhh,
    const float* __restrict__ Zb, const float* __restrict__ gx2b,
    float* __restrict__ H, int N){
  int n = blockIdx.x;
  int t = threadIdx.x; int b = t >> 5; int h = t & 31;
  __shared__ float sh[3][128];
  sh[0][t] = thr0[(size_t)n*128 + t];
  sh[1][t] = thr1[(size_t)n*128 + t];
  sh[2][t] = thr2[(size_t)n*128 + t];
  __syncthreads();
  float gh = bhh[h];
  #pragma unroll
  for (int k = 0; k < 3; ++k){
    #pragma unroll
    for (int o = 0; o < 32; ++o){
      gh = fmaf(sh[k][b*32 + o], Whh[(k*32 + o)*32 + h], gh);
    }
  }
  size_t idx = (size_t)n*128 + t;
  float Ht = tanhf(gx2b[idx] + gh);
  float Zv = Zb[idx];
  H[idx] = Zv*H[idx] + (1.f - Zv)*Ht;
}

// ---------------- readout ----------------
__global__ void readout_kernel(const float* __restrict__ H1, const float* __restrict__ muW,
                               const float* __restrict__ mub, const float* __restrict__ sgW,
                               const float* __restrict__ sgb, float* __restrict__ outp, int N){
  int idx = blockIdx.x*blockDim.x + threadIdx.x;   // over 4*N
  if (idx >= 4*N) return;
  int b = idx / N, n = idx - b*N;
  const float* h = H1 + (size_t)n*128 + b*32;
  float m0 = mub[0], m1 = mub[1], s0 = sgb[0], s1 = sgb[1];
  #pragma unroll
  for (int o = 0; o < 32; ++o){
    float v = h[o];
    m0 = fmaf(v, muW[o*2+0], m0);
    m1 = fmaf(v, muW[o*2+1], m1);
    s0 = fmaf(v, sgW[o*2+0], s0);
    s1 = fmaf(v, sgW[o*2+1], s1);
  }
  size_t base = (size_t)(b*N + n)*2;
  outp[base]   = sigmoidf_(m0);
  outp[base+1] = sigmoidf_(m1);
  size_t sb = (size_t)8*N + base;
  outp[sb]   = (s0 > 15.f) ? s0 : log1pf(__expf(s0));
  outp[sb+1] = (s1 > 15.f) ? s1 : log1pf(__expf(s1));
}

__global__ void mean_kernel(const float* __restrict__ H1, float* __restrict__ mixsum, int N){
  int t = threadIdx.x;   // 128 = (b,o)
  int chunk = (N + gridDim.x - 1) / gridDim.x;
  int n0 = blockIdx.x*chunk, n1 = min(N, n0 + chunk);
  float acc = 0.f;
  for (int n = n0; n < n1; ++n) acc += H1[(size_t)n*128 + t];
  atomicAdd(mixsum + t, acc);
}

__global__ void softmax_kernel(const float* __restrict__ mixsum, float* __restrict__ outp,
                               float invN){
  __shared__ float v[128];
  __shared__ float e[128];
  int t = threadIdx.x; int b = t >> 5;
  float m = mixsum[t]*invN;
  v[t] = m; __syncthreads();
  float mx = -1e30f;
  for (int o = 0; o < 32; ++o) mx = fmaxf(mx, v[b*32 + o]);
  float ex = __expf(m - mx);
  e[t] = ex; __syncthreads();
  float s = 0.f;
  for (int o = 0; o < 32; ++o) s += e[b*32 + o];
  outp[t] = ex / s;
}

// ---------------------------------------------------------------------------

extern "C" void kernel_launch(void* const* d_in, const int* in_sizes, int n_in,
                              void* d_out, int out_size, void* d_ws, size_t ws_size,
                              hipStream_t stream){
  const float* in0  = (const float*)d_in[0];
  const void*  eidx = d_in[1];
  const float* ew   = (const float*)d_in[2];
  const float* Wx0  = (const float*)d_in[3];
  const float* Wh0  = (const float*)d_in[4];
  const float* bx0  = (const float*)d_in[5];
  const float* bh0  = (const float*)d_in[6];
  const float* Wx1  = (const float*)d_in[7];
  const float* Wh1  = (const float*)d_in[8];
  const float* bx1  = (const float*)d_in[9];
  const float* bh1  = (const float*)d_in[10];
  const float* muW  = (const float*)d_in[11];
  const float* mub  = (const float*)d_in[12];
  const float* sgW  = (const float*)d_in[13];
  const float* sgb  = (const float*)d_in[14];
  float* outp = (float*)d_out;

  const int N = in_sizes[0] / (4*12*8);
  const int E = in_sizes[1] / 2;

  // ---- carve workspace ----
  char* w = (char*)d_ws;
  size_t off = 0;
  auto alloc = [&](size_t bytes)->void*{
    void* p = w + off;
    off += (bytes + 255) & ~(size_t)255;
    return p;
  };
  int*   row32   = (int*)  alloc((size_t)E*4);
  int*   col32   = (int*)  alloc((size_t)E*4);
  int*   csr_src = (int*)  alloc((size_t)E*4);
  float* csr_val = (float*)alloc((size_t)E*4);
  int*   ptrv    = (int*)  alloc((size_t)(N+1)*4);
  int*   cnt     = (int*)  alloc((size_t)N*4);
  int*   cnt2    = (int*)  alloc((size_t)N*4);
  float* deg     = (float*)alloc((size_t)N*4);
  float* dinv    = (float*)alloc((size_t)N*4);
  float* dgv     = (float*)alloc((size_t)N*4);
  int*   flag    = (int*)  alloc(256);
  float* mixsum  = (float*)alloc(512);
  float* xb0     = (float*)alloc((size_t)N*32*4);
  float* xb1     = (float*)alloc((size_t)N*128*4);
  float* xb2     = (float*)alloc((size_t)N*128*4);
  float* th1     = (float*)alloc((size_t)N*128*4);
  float* th2     = (float*)alloc((size_t)N*128*4);
  float* Zb      = (float*)alloc((size_t)N*128*4);
  float* gx2b    = (float*)alloc((size_t)N*128*4);
  float* HRb     = (float*)alloc((size_t)N*128*4);
  float* H0      = (float*)alloc((size_t)N*128*4);
  float* H1      = (float*)alloc((size_t)N*128*4);

  // ---- zero-init (ws is poisoned 0xAA before each call) ----
  hipMemsetAsync(flag,   0, 4, stream);
  hipMemsetAsync(deg,    0, (size_t)N*4, stream);
  hipMemsetAsync(cnt,    0, (size_t)N*4, stream);
  hipMemsetAsync(cnt2,   0, (size_t)N*4, stream);
  hipMemsetAsync(H0,     0, (size_t)N*128*4, stream);
  hipMemsetAsync(H1,     0, (size_t)N*128*4, stream);
  hipMemsetAsync(mixsum, 0, 512, stream);

  // ---- preprocessing: dtype detect, degrees, CSR build ----
  {
    int ndw = 4096;            // both int32 (2E dwords) and int64 (4E) buffers cover this
    if (ndw > 2*E) ndw = 2*E;
    int nthread = ndw/2 + 1;
    detect_kernel<<<(nthread+255)/256, 256, 0, stream>>>((const unsigned*)eidx, ndw, flag);
  }
  convert_kernel<<<(E+255)/256, 256, 0, stream>>>(eidx, ew, E, flag, row32, col32, deg, cnt);
  node_prep_kernel<<<(N+255)/256, 256, 0, stream>>>(deg, dinv, dgv, N);
  scan_kernel<<<1, 1024, 0, stream>>>(cnt, ptrv, N);
  fill_kernel<<<(E+255)/256, 256, 0, stream>>>(row32, col32, ew, dinv, ptrv, cnt2,
                                               csr_src, csr_val, E);

  const int gSp128 = N;          // 1 node / 128 threads
  const int gSp32  = (N+3)/4;    // 4 nodes / 128 threads

  for (int t = 0; t < 12; ++t){
    // ================= layer 0 (Fin=8) =================
    transpose_x_kernel<<<(N*32+255)/256, 256, 0, stream>>>(in0, xb0, N, t);
    // X basis
    spmm_kernel<32><<<gSp32,128,0,stream>>>(ptrv,csr_src,csr_val,dgv, xb0,nullptr,xb1, N,32, 1.f, 0.f);
    spmm_kernel<32><<<gSp32,128,0,stream>>>(ptrv,csr_src,csr_val,dgv, xb1,xb0,   xb2, N,32, 2.f,-1.f);
    // H basis
    spmm_kernel<128><<<gSp128,128,0,stream>>>(ptrv,csr_src,csr_val,dgv, H0,nullptr,th1, N,128, 1.f, 0.f);
    spmm_kernel<128><<<gSp128,128,0,stream>>>(ptrv,csr_src,csr_val,dgv, th1,H0,   th2, N,128, 2.f,-1.f);
    gateA_kernel<8><<<N,128,0,stream>>>(xb0,xb1,xb2, 32, H0,th1,th2,
                                        Wx0,bx0, Wh0, Wh0+3072, bh0, bh0+32,
                                        Zb,gx2b,HRb, N);
    // HR basis (reuse th1/th2)
    spmm_kernel<128><<<gSp128,128,0,stream>>>(ptrv,csr_src,csr_val,dgv, HRb,nullptr,th1, N,128, 1.f, 0.f);
    spmm_kernel<128><<<gSp128,128,0,stream>>>(ptrv,csr_src,csr_val,dgv, th1,HRb,  th2, N,128, 2.f,-1.f);
    gateB_kernel<<<N,128,0,stream>>>(HRb,th1,th2, Wh0+6144, bh0+64, Zb,gx2b, H0, N);

    // ================= layer 1 (Fin=32, input = H0) =================
    spmm_kernel<128><<<gSp128,128,0,stream>>>(ptrv,csr_src,csr_val,dgv, H0,nullptr,xb1, N,128, 1.f, 0.f);
    spmm_kernel<128><<<gSp128,128,0,stream>>>(ptrv,csr_src,csr_val,dgv, xb1,H0,   xb2, N,128, 2.f,-1.f);
    spmm_kernel<128><<<gSp128,128,0,stream>>>(ptrv,csr_src,csr_val,dgv, H1,nullptr,th1, N,128, 1.f, 0.f);
    spmm_kernel<128><<<gSp128,128,0,stream>>>(ptrv,csr_src,csr_val,dgv, th1,H1,   th2, N,128, 2.f,-1.f);
    gateA_kernel<32><<<N,128,0,stream>>>(H0,xb1,xb2, 128, H1,th1,th2,
                                         Wx1,bx1, Wh1, Wh1+3072, bh1, bh1+32,
                                         Zb,gx2b,HRb, N);
    spmm_kernel<128><<<gSp128,128,0,stream>>>(ptrv,csr_src,csr_val,dgv, HRb,nullptr,th1, N,128, 1.f, 0.f);
    spmm_kernel<128><<<gSp128,128,0,stream>>>(ptrv,csr_src,csr_val,dgv, th1,HRb,  th2, N,128, 2.f,-1.f);
    gateB_kernel<<<N,128,0,stream>>>(HRb,th1,th2, Wh1+6144, bh1+64, Zb,gx2b, H1, N);
  }

  // ---- readout ----
  readout_kernel<<<(4*N+255)/256, 256, 0, stream>>>(H1, muW, mub, sgW, sgb, outp, N);
  mean_kernel<<<256, 128, 0, stream>>>(H1, mixsum, N);
  softmax_kernel<<<1, 128, 0, stream>>>(mixsum, outp + (size_t)16*N, 1.0f/(float)N);
}